// Round 2
// baseline (1375.682 us; speedup 1.0000x reference)
//
#include <hip/hip_runtime.h>
#include <cstdint>
#include <math.h>

#define NROWS_MAX 4096
#define B      64
#define DF     172
#define DE     64
#define HDIM   256
#define DLINK  320
#define KSAMP  16
#define THREADS 512

// ---------------- threefry2x32 (bit-exact vs JAX) ----------------
__device__ __forceinline__ uint32_t rotl32(uint32_t x, int d) {
  return (x << d) | (x >> (32 - d));
}

__device__ __forceinline__ void threefry2x32(uint32_t k0, uint32_t k1,
                                             uint32_t& x0, uint32_t& x1) {
  const uint32_t ks0 = k0, ks1 = k1, ks2 = k0 ^ k1 ^ 0x1BD11BDAu;
  x0 += ks0; x1 += ks1;
#define TF_R4(a,b,c,d) \
  x0 += x1; x1 = rotl32(x1, a); x1 ^= x0; \
  x0 += x1; x1 = rotl32(x1, b); x1 ^= x0; \
  x0 += x1; x1 = rotl32(x1, c); x1 ^= x0; \
  x0 += x1; x1 = rotl32(x1, d); x1 ^= x0;
  TF_R4(13,15,26,6)  x0 += ks1; x1 += ks2 + 1u;
  TF_R4(17,29,16,24) x0 += ks2; x1 += ks0 + 2u;
  TF_R4(13,15,26,6)  x0 += ks0; x1 += ks1 + 3u;
  TF_R4(17,29,16,24) x0 += ks1; x1 += ks2 + 4u;
  TF_R4(13,15,26,6)  x0 += ks2; x1 += ks0 + 5u;
#undef TF_R4
}

// ---------------- encode GEMM: [64 x 172] @ [172 x 64] + bias, relu ----------------
// thread layout: tb = t>>4 (32 groups, 2 b each), jt = t&15 (4 j each)
__device__ __forceinline__ void enc_gemm(const float* __restrict__ W,
                                         const float* __restrict__ bias,
                                         int col_off, int t,
                                         const float* nfl, float* lnk) {
  const int tb = t >> 4;
  const int jt = t & 15;
  const int b0 = tb * 2, j0 = jt * 4;
  const float4 bv = *(const float4*)(bias + j0);
  float acc[2][4];
  acc[0][0] = bv.x; acc[0][1] = bv.y; acc[0][2] = bv.z; acc[0][3] = bv.w;
  acc[1][0] = bv.x; acc[1][1] = bv.y; acc[1][2] = bv.z; acc[1][3] = bv.w;
  const float4* nf4 = (const float4*)nfl;   // [64][43]
  const float4* W4  = (const float4*)W;     // [172][16]
  for (int dd = 0; dd < 43; ++dd) {
    float4 a0 = nf4[b0 * 43 + dd];
    float4 a1 = nf4[(b0 + 1) * 43 + dd];
    float A0[4] = {a0.x, a0.y, a0.z, a0.w};
    float A1[4] = {a1.x, a1.y, a1.z, a1.w};
#pragma unroll
    for (int r = 0; r < 4; ++r) {
      float4 wv = W4[(dd * 4 + r) * 16 + jt];
      acc[0][0] = fmaf(A0[r], wv.x, acc[0][0]);
      acc[0][1] = fmaf(A0[r], wv.y, acc[0][1]);
      acc[0][2] = fmaf(A0[r], wv.z, acc[0][2]);
      acc[0][3] = fmaf(A0[r], wv.w, acc[0][3]);
      acc[1][0] = fmaf(A1[r], wv.x, acc[1][0]);
      acc[1][1] = fmaf(A1[r], wv.y, acc[1][1]);
      acc[1][2] = fmaf(A1[r], wv.z, acc[1][2]);
      acc[1][3] = fmaf(A1[r], wv.w, acc[1][3]);
    }
  }
#pragma unroll
  for (int i = 0; i < 2; ++i) {
    float4 s;
    s.x = fmaxf(acc[i][0], 0.0f);
    s.y = fmaxf(acc[i][1], 0.0f);
    s.z = fmaxf(acc[i][2], 0.0f);
    s.w = fmaxf(acc[i][3], 0.0f);
    *(float4*)&lnk[(b0 + i) * DLINK + col_off + j0] = s;
  }
}

__global__ __launch_bounds__(THREADS, 1)
void AdaptSampler_kernel(const float* __restrict__ rootf,   // [n,172]
                         const float* __restrict__ root_ts, // [n]
                         const float* __restrict__ nf,      // [n,64,172]
                         const float* __restrict__ ef,      // [n,64,172]
                         const float* __restrict__ nts,     // [n,64]
                         const int*   __restrict__ nid,     // [n,64]
                         const float* __restrict__ Wn,      // [172,64]
                         const float* __restrict__ bn,      // [64]
                         const float* __restrict__ We,      // [172,64]
                         const float* __restrict__ be,      // [64]
                         const float* __restrict__ Wl,      // [320,256]
                         const float* __restrict__ Wr,      // [192,256]
                         float* __restrict__ out_probs,     // [n,64]
                         float* __restrict__ out_action,    // [n,16] (as float)
                         int n_total)
{
  __shared__ float link_lds[B * DLINK];   // 81920 B
  __shared__ float nf_lds[B * DF];        // 44032 B
  __shared__ float hroot_lds[HDIM];
  __shared__ float rootenc_lds[192];
  __shared__ float w_lds[DE];
  __shared__ float ts_lds[B];
  __shared__ int   nid_lds[B];
  __shared__ float freq_lds[B];
  __shared__ float sc_lds[B];

  const int n = blockIdx.x;
  const int t = threadIdx.x;

  // ---------------- Phase 0 ----------------
  if (t < B) {
    // basis: f32-rounded from f64 (mirrors np.linspace(f64) -> 10** -> 1/ -> astype(f32))
    double e = 9.0 * (double)t / 63.0;
    w_lds[t] = (float)(1.0 / pow(10.0, e));
    nid_lds[t] = nid[n * B + t];
    ts_lds[t]  = nts[n * B + t];
  }
  {
    const float4* src = (const float4*)(nf + (size_t)n * B * DF);
    float4* dst = (float4*)nf_lds;
    for (int i = t; i < B * DF / 4; i += THREADS) dst[i] = src[i];
  }
  if (t < B) {  // root_feat = relu(root_nf @ Wn + bn)
    float acc = bn[t];
    const float* r = rootf + (size_t)n * DF;
    for (int d = 0; d < DF; ++d) acc = fmaf(r[d], Wn[d * 64 + t], acc);
    rootenc_lds[t] = fmaxf(acc, 0.0f);
    rootenc_lds[64 + t] = 1.0f;              // cos(0 * w) = 1
  }
  __syncthreads();

  // ---------------- Phase 1: time_enc, iden, freq, cos(w), node GEMM ----------------
  if (t < B) {
    rootenc_lds[128 + t] = cosf(w_lds[t]);   // cos(1 * w)
    int c = 0, my = nid_lds[t];
    for (int b2 = 0; b2 < B; ++b2) c += (nid_lds[b2] == my) ? 1 : 0;
    freq_lds[t] = (float)c * (1.0f / 64.0f);
  }
  {
    const float rts = root_ts[n];
#pragma unroll
    for (int q = 0; q < 8; ++q) {
      int idx = t * 8 + q;                   // 0..4095
      int b = idx >> 6, d = idx & 63;
      float dt = rts - ts_lds[b];
      link_lds[b * DLINK + 128 + d] = cosf(dt * w_lds[d]);
      link_lds[b * DLINK + 256 + d] = (nid_lds[b] == nid_lds[d]) ? 1.0f : 0.0f;
    }
  }
  enc_gemm(Wn, bn, 0, t, nf_lds, link_lds);
  __syncthreads();

  // ---------------- Phase 2: stage EF, freq_enc, h_root ----------------
  {
    const float4* src = (const float4*)(ef + (size_t)n * B * DF);
    float4* dst = (float4*)nf_lds;
    for (int i = t; i < B * DF / 4; i += THREADS) dst[i] = src[i];
  }
#pragma unroll
  for (int q = 0; q < 8; ++q) {
    int idx = t * 8 + q;
    int b = idx >> 6, d = idx & 63;
    link_lds[b * DLINK + 192 + d] = cosf(freq_lds[b] * w_lds[d]);
  }
  if (t < HDIM) {
    float acc = 0.0f;
    for (int d = 0; d < 192; ++d) acc = fmaf(rootenc_lds[d], Wr[d * HDIM + t], acc);
    hroot_lds[t] = fmaxf(acc, 0.0f);
  }
  __syncthreads();

  // ---------------- Phase 3: edge GEMM ----------------
  enc_gemm(We, be, 64, t, nf_lds, link_lds);
  __syncthreads();

  // ---------------- Phase 4: link GEMM fused with h_root dot -> scores ----------------
  {
    const int th = t & 31;                   // h-slices: [4*th..4*th+3] and [128+4*th..]
    const int tb = t >> 5;                   // 16 groups, 4 b each
    const int b0 = tb * 4;
    float acc[4][8];
#pragma unroll
    for (int i = 0; i < 4; ++i)
#pragma unroll
      for (int j = 0; j < 8; ++j) acc[i][j] = 0.0f;
    const float4* L4  = (const float4*)link_lds;  // [64][80]
    const float4* Wl4 = (const float4*)Wl;        // [320][64]
    for (int dd = 0; dd < 80; ++dd) {
      float Lr[4][4];
#pragma unroll
      for (int i = 0; i < 4; ++i) {
        float4 lv = L4[(b0 + i) * 80 + dd];
        Lr[i][0] = lv.x; Lr[i][1] = lv.y; Lr[i][2] = lv.z; Lr[i][3] = lv.w;
      }
#pragma unroll
      for (int r = 0; r < 4; ++r) {
        float4 w0 = Wl4[(dd * 4 + r) * 64 + th];
        float4 w1 = Wl4[(dd * 4 + r) * 64 + 32 + th];
#pragma unroll
        for (int i = 0; i < 4; ++i) {
          acc[i][0] = fmaf(Lr[i][r], w0.x, acc[i][0]);
          acc[i][1] = fmaf(Lr[i][r], w0.y, acc[i][1]);
          acc[i][2] = fmaf(Lr[i][r], w0.z, acc[i][2]);
          acc[i][3] = fmaf(Lr[i][r], w0.w, acc[i][3]);
          acc[i][4] = fmaf(Lr[i][r], w1.x, acc[i][4]);
          acc[i][5] = fmaf(Lr[i][r], w1.y, acc[i][5]);
          acc[i][6] = fmaf(Lr[i][r], w1.z, acc[i][6]);
          acc[i][7] = fmaf(Lr[i][r], w1.w, acc[i][7]);
        }
      }
    }
#pragma unroll
    for (int i = 0; i < 4; ++i) {
      float s = 0.0f;
#pragma unroll
      for (int j = 0; j < 4; ++j)
        s = fmaf(fmaxf(acc[i][j], 0.0f), hroot_lds[4 * th + j], s);
#pragma unroll
      for (int j = 0; j < 4; ++j)
        s = fmaf(fmaxf(acc[i][4 + j], 0.0f), hroot_lds[128 + 4 * th + j], s);
#pragma unroll
      for (int m = 16; m >= 1; m >>= 1) s += __shfl_xor(s, m);
      if (th == 0) sc_lds[b0 + i] = s;
    }
  }
  __syncthreads();

  // ---------------- Phase 5: softmax + gumbel + top-16 (wave 0) ----------------
  if (t < B) {
    float s = sc_lds[t] * 0.0625f;   // / sqrt(256)
    float m = s;
#pragma unroll
    for (int mm = 32; mm >= 1; mm >>= 1) m = fmaxf(m, __shfl_xor(m, mm));
    float e = expf(s - m);
    float sum = e;
#pragma unroll
    for (int mm = 32; mm >= 1; mm >>= 1) sum += __shfl_xor(sum, mm);
    float p = e / sum;
    out_probs[(size_t)n * B + t] = p;

    // gumbel from threefry — PARTITIONABLE scheme (jax_threefry_partitionable=True,
    // default since JAX 0.4.36): per element i, block input = (hi32(i), lo32(i)) = (0, i),
    // 32-bit draw = out0 ^ out1.
    uint32_t i = (uint32_t)(n * B + t);
    uint32_t x0 = 0u, x1 = i;
    threefry2x32(0u, 42u, x0, x1);
    uint32_t bits = x0 ^ x1;
    float f = __uint_as_float((bits >> 9) | 0x3f800000u) - 1.0f;
    const float TINY = 1.1754943508222875e-38f;
    float u = fmaxf(f * (1.0f - TINY) + TINY, TINY);
    float g = -logf(-logf(u));
    float keyv = logf(p + 1e-20f) + g;

    float v = keyv;
    for (int k = 0; k < KSAMP; ++k) {
      float bv = v; int bi = t;
#pragma unroll
      for (int mm = 32; mm >= 1; mm >>= 1) {
        float ov = __shfl_xor(bv, mm);
        int   oi = __shfl_xor(bi, mm);
        if (ov > bv || (ov == bv && oi < bi)) { bv = ov; bi = oi; }
      }
      if (t == 0) out_action[(size_t)n * KSAMP + k] = (float)bi;
      if (t == bi) v = -3.402823466e+38f;
    }
  }
}

extern "C" void kernel_launch(void* const* d_in, const int* in_sizes, int n_in,
                              void* d_out, int out_size, void* d_ws, size_t ws_size,
                              hipStream_t stream) {
  const float* rootf = (const float*)d_in[0];
  const float* rts   = (const float*)d_in[1];
  const float* nf    = (const float*)d_in[2];
  const float* ef    = (const float*)d_in[3];
  const float* nts   = (const float*)d_in[4];
  const int*   nid   = (const int*)d_in[5];
  const float* Wn    = (const float*)d_in[6];
  const float* bn    = (const float*)d_in[7];
  const float* We    = (const float*)d_in[8];
  const float* be    = (const float*)d_in[9];
  const float* Wl    = (const float*)d_in[10];
  const float* Wr    = (const float*)d_in[11];

  const int n = in_sizes[1];                   // 4096 rows
  float* probs  = (float*)d_out;               // [n,64] f32
  float* action = probs + (size_t)n * B;       // [n,16] written as f32 values

  AdaptSampler_kernel<<<dim3(n), dim3(THREADS), 0, stream>>>(
      rootf, rts, nf, ef, nts, nid, Wn, bn, We, be, Wl, Wr, probs, action, n);
}

// Round 3
// 1316.938 us; speedup vs baseline: 1.0446x; 1.0446x over previous
//
#include <hip/hip_runtime.h>
#include <cstdint>
#include <math.h>

#define B       64
#define DF      172
#define DE      64
#define HDIM    256
#define KSAMP   16
#define THREADS 512

typedef const __attribute__((address_space(1))) unsigned int* gp_t;
typedef __attribute__((address_space(3))) unsigned int* lp_t;

// ---------------- threefry2x32 (bit-exact vs JAX, partitionable scheme) ----------------
__device__ __forceinline__ uint32_t rotl32(uint32_t x, int d) {
  return (x << d) | (x >> (32 - d));
}

__device__ __forceinline__ void threefry2x32(uint32_t k0, uint32_t k1,
                                             uint32_t& x0, uint32_t& x1) {
  const uint32_t ks0 = k0, ks1 = k1, ks2 = k0 ^ k1 ^ 0x1BD11BDAu;
  x0 += ks0; x1 += ks1;
#define TF_R4(a,b,c,d) \
  x0 += x1; x1 = rotl32(x1, a); x1 ^= x0; \
  x0 += x1; x1 = rotl32(x1, b); x1 ^= x0; \
  x0 += x1; x1 = rotl32(x1, c); x1 ^= x0; \
  x0 += x1; x1 = rotl32(x1, d); x1 ^= x0;
  TF_R4(13,15,26,6)  x0 += ks1; x1 += ks2 + 1u;
  TF_R4(17,29,16,24) x0 += ks2; x1 += ks0 + 2u;
  TF_R4(13,15,26,6)  x0 += ks0; x1 += ks1 + 3u;
  TF_R4(17,29,16,24) x0 += ks1; x1 += ks2 + 4u;
  TF_R4(13,15,26,6)  x0 += ks2; x1 += ks0 + 5u;
#undef TF_R4
}

// ---------------- async stage 44032 B (2752 float4) global -> LDS ----------------
__device__ __forceinline__ void stage_async(const float* __restrict__ g,
                                            float* l, int t) {
#pragma unroll
  for (int it = 0; it < 5; ++it) {
    const int i  = it * 512 + t;
    const int ib = it * 512 + (t & ~63);   // wave-uniform LDS base
    __builtin_amdgcn_global_load_lds((gp_t)(g + i * 4), (lp_t)(l + ib * 4), 16, 0, 0);
  }
  if (t < 192) {                           // tail: 3 full waves
    const int i  = 2560 + t;
    const int ib = 2560 + (t & ~63);
    __builtin_amdgcn_global_load_lds((gp_t)(g + i * 4), (lp_t)(l + ib * 4), 16, 0, 0);
  }
}

// ---------------- encode GEMM: [64 x 172] @ [172 x 64] + bias, relu ----------------
// thread (b = t>>3, g = t&7): 1 row, 8 cols
__device__ __forceinline__ void enc_gemm(const float* __restrict__ stage,
                                         const float* __restrict__ W,
                                         const float* __restrict__ bias,
                                         float* __restrict__ out,
                                         int b, int g) {
  const float4 bi0 = ((const float4*)bias)[g * 2];
  const float4 bi1 = ((const float4*)bias)[g * 2 + 1];
  float a0 = bi0.x, a1 = bi0.y, a2 = bi0.z, a3 = bi0.w;
  float a4 = bi1.x, a5 = bi1.y, a6 = bi1.z, a7 = bi1.w;
  const float* arow = stage + b * DF;
  const float4* W4 = (const float4*)W;     // [172][16]
#pragma unroll 4
  for (int k = 0; k < DF; ++k) {
    const float a = arow[k];
    const float4 w0 = W4[k * 16 + g * 2];
    const float4 w1 = W4[k * 16 + g * 2 + 1];
    a0 = fmaf(a, w0.x, a0); a1 = fmaf(a, w0.y, a1);
    a2 = fmaf(a, w0.z, a2); a3 = fmaf(a, w0.w, a3);
    a4 = fmaf(a, w1.x, a4); a5 = fmaf(a, w1.y, a5);
    a6 = fmaf(a, w1.z, a6); a7 = fmaf(a, w1.w, a7);
  }
  float4 o0 = make_float4(fmaxf(a0, 0.f), fmaxf(a1, 0.f), fmaxf(a2, 0.f), fmaxf(a3, 0.f));
  float4 o1 = make_float4(fmaxf(a4, 0.f), fmaxf(a5, 0.f), fmaxf(a6, 0.f), fmaxf(a7, 0.f));
  ((float4*)out)[b * 16 + g * 2]     = o0;
  ((float4*)out)[b * 16 + g * 2 + 1] = o1;
}

// ---------------- h_link piece accumulate: acc[4 rows][8 h] += enc @ Wl[off:off+64] ----------------
__device__ __forceinline__ void accum_piece(float (&acc)[4][8],
                                            const float* __restrict__ enc, int r4,
                                            const float4* __restrict__ Wl4, int off, int th) {
#pragma unroll 2
  for (int d = 0; d < 64; ++d) {
    float e[4];
#pragma unroll
    for (int i = 0; i < 4; ++i) e[i] = enc[(r4 + i) * 64 + d];   // broadcast reads
    const float4 w0 = Wl4[(off + d) * 64 + th * 2];
    const float4 w1 = Wl4[(off + d) * 64 + th * 2 + 1];
#pragma unroll
    for (int i = 0; i < 4; ++i) {
      acc[i][0] = fmaf(e[i], w0.x, acc[i][0]);
      acc[i][1] = fmaf(e[i], w0.y, acc[i][1]);
      acc[i][2] = fmaf(e[i], w0.z, acc[i][2]);
      acc[i][3] = fmaf(e[i], w0.w, acc[i][3]);
      acc[i][4] = fmaf(e[i], w1.x, acc[i][4]);
      acc[i][5] = fmaf(e[i], w1.y, acc[i][5]);
      acc[i][6] = fmaf(e[i], w1.z, acc[i][6]);
      acc[i][7] = fmaf(e[i], w1.w, acc[i][7]);
    }
  }
}

__global__ __launch_bounds__(THREADS, 4)
void AdaptSampler_kernel(const float* __restrict__ rootf,   // [n,172]
                         const float* __restrict__ root_ts, // [n]
                         const float* __restrict__ nf,      // [n,64,172]
                         const float* __restrict__ ef,      // [n,64,172]
                         const float* __restrict__ nts,     // [n,64]
                         const int*   __restrict__ nid,     // [n,64]
                         const float* __restrict__ Wn,      // [172,64]
                         const float* __restrict__ bn,      // [64]
                         const float* __restrict__ We,      // [172,64]
                         const float* __restrict__ be,      // [64]
                         const float* __restrict__ Wl,      // [320,256]
                         const float* __restrict__ Wr,      // [192,256]
                         float* __restrict__ out_probs,     // [n,64]
                         float* __restrict__ out_action)    // [n,16] (as float)
{
  __shared__ float nf_stage[B * DF];    // 44032 B: nf then ef
  __shared__ float encA[B * DE];        // 16384 B: node_enc -> edge_enc -> freq_enc
  __shared__ float encB[B * DE];        // 16384 B: time_enc
  __shared__ float hroot_lds[HDIM];     // 1024 B
  __shared__ float rootenc_lds[192];
  __shared__ float w_lds[DE];
  __shared__ float ts_lds[B];
  __shared__ int   nid_lds[B];
  __shared__ float freq_lds[B];
  __shared__ float sc_lds[B];
  // total: 79872 B -> 2 blocks/CU

  const int n = blockIdx.x;
  const int t = threadIdx.x;
  const int r  = t >> 5;      // 16 row-groups of 4 rows
  const int th = t & 31;      // 32 h-threads, 8 h each
  const int r4 = r * 4;
  const int be_ = t >> 3;     // enc row
  const int ge_ = t & 7;      // enc col-group
  const float4* Wl4 = (const float4*)Wl;  // [320][64]

  // ---------------- P0: stage nf; basis/nid/ts ----------------
  stage_async(nf + (size_t)n * B * DF, nf_stage, t);
  if (t < B) {
    double e = 9.0 * (double)t / 63.0;   // np.linspace in f64
    w_lds[t] = (float)(1.0 / pow(10.0, e));
    nid_lds[t] = nid[n * B + t];
    ts_lds[t]  = nts[n * B + t];
  }
  __syncthreads();

  // ---------------- P1: node_enc -> encA, time_enc -> encB, root pieces ----------------
  enc_gemm(nf_stage, Wn, bn, encA, be_, ge_);
  {
    const float rts = root_ts[n];
#pragma unroll
    for (int q = 0; q < 8; ++q) {
      const int idx = t * 8 + q;
      const int bb = idx >> 6, dd = idx & 63;
      encB[idx] = cosf((rts - ts_lds[bb]) * w_lds[dd]);
    }
  }
  if (t < B) {
    float a = bn[t];
    const float* rr = rootf + (size_t)n * DF;
    for (int d = 0; d < DF; ++d) a = fmaf(rr[d], Wn[d * 64 + t], a);
    rootenc_lds[t]       = fmaxf(a, 0.0f);
    rootenc_lds[64 + t]  = 1.0f;            // cos(0*w)
    rootenc_lds[128 + t] = cosf(w_lds[t]);  // cos(1*w)
    int c = 0; const int my = nid_lds[t];
    for (int j = 0; j < B; ++j) c += (nid_lds[j] == my) ? 1 : 0;
    freq_lds[t] = (float)c * 0.015625f;
  }
  __syncthreads();

  // ---------------- P2: issue ef stage; h_root; accum node (d 0..63) ----------------
  stage_async(ef + (size_t)n * B * DF, nf_stage, t);
  float acc[4][8];
#pragma unroll
  for (int i = 0; i < 4; ++i)
#pragma unroll
    for (int j = 0; j < 8; ++j) acc[i][j] = 0.0f;
  {
    const int h = t >> 1, hf = t & 1;
    float a = 0.0f;
    for (int d = hf * 96; d < hf * 96 + 96; ++d)
      a = fmaf(rootenc_lds[d], Wr[d * HDIM + h], a);
    a += __shfl_xor(a, 1);
    if (hf == 0) hroot_lds[h] = fmaxf(a, 0.0f);
  }
  accum_piece(acc, encA, r4, Wl4, 0, th);
  __syncthreads();

  // ---------------- P3: edge_enc -> encA ----------------
  enc_gemm(nf_stage, We, be, encA, be_, ge_);
  __syncthreads();

  // ---------------- P4: accum edge (d 64..127) ----------------
  accum_piece(acc, encA, r4, Wl4, 64, th);
  __syncthreads();

  // ---------------- P5: freq_enc -> encA ----------------
#pragma unroll
  for (int q = 0; q < 8; ++q) {
    const int idx = t * 8 + q;
    const int bb = idx >> 6, dd = idx & 63;
    encA[idx] = cosf(freq_lds[bb] * w_lds[dd]);
  }
  __syncthreads();

  // ---------------- P6: accum time (128..191), freq (192..255), iden (256..319) ----------------
  accum_piece(acc, encB, r4, Wl4, 128, th);
  accum_piece(acc, encA, r4, Wl4, 192, th);
  {
    int nr[4];
#pragma unroll
    for (int i = 0; i < 4; ++i) nr[i] = nid_lds[r4 + i];
#pragma unroll 2
    for (int d = 0; d < 64; ++d) {
      const int nd = nid_lds[d];
      const float4 w0 = Wl4[(256 + d) * 64 + th * 2];
      const float4 w1 = Wl4[(256 + d) * 64 + th * 2 + 1];
#pragma unroll
      for (int i = 0; i < 4; ++i) {
        const float e = (nr[i] == nd) ? 1.0f : 0.0f;
        acc[i][0] = fmaf(e, w0.x, acc[i][0]);
        acc[i][1] = fmaf(e, w0.y, acc[i][1]);
        acc[i][2] = fmaf(e, w0.z, acc[i][2]);
        acc[i][3] = fmaf(e, w0.w, acc[i][3]);
        acc[i][4] = fmaf(e, w1.x, acc[i][4]);
        acc[i][5] = fmaf(e, w1.y, acc[i][5]);
        acc[i][6] = fmaf(e, w1.z, acc[i][6]);
        acc[i][7] = fmaf(e, w1.w, acc[i][7]);
      }
    }
  }

  // ---------------- P7: scores = relu(h_link) . h_root, reduce over th ----------------
#pragma unroll
  for (int i = 0; i < 4; ++i) {
    float s = 0.0f;
#pragma unroll
    for (int j = 0; j < 8; ++j)
      s = fmaf(fmaxf(acc[i][j], 0.0f), hroot_lds[th * 8 + j], s);
#pragma unroll
    for (int m = 16; m >= 1; m >>= 1) s += __shfl_xor(s, m);
    if (th == 0) sc_lds[r4 + i] = s;
  }
  __syncthreads();

  // ---------------- P8: softmax + gumbel + top-16 (wave 0) ----------------
  if (t < B) {
    float s = sc_lds[t] * 0.0625f;   // / sqrt(256)
    float m = s;
#pragma unroll
    for (int mm = 32; mm >= 1; mm >>= 1) m = fmaxf(m, __shfl_xor(m, mm));
    float e = expf(s - m);
    float sum = e;
#pragma unroll
    for (int mm = 32; mm >= 1; mm >>= 1) sum += __shfl_xor(sum, mm);
    float p = e / sum;
    out_probs[(size_t)n * B + t] = p;

    // partitionable threefry: block input (0, i), draw = out0 ^ out1
    uint32_t i = (uint32_t)(n * B + t);
    uint32_t x0 = 0u, x1 = i;
    threefry2x32(0u, 42u, x0, x1);
    uint32_t bits = x0 ^ x1;
    float f = __uint_as_float((bits >> 9) | 0x3f800000u) - 1.0f;
    const float TINY = 1.1754943508222875e-38f;
    float u = fmaxf(f * (1.0f - TINY) + TINY, TINY);
    float g = -logf(-logf(u));
    float keyv = logf(p + 1e-20f) + g;

    float v = keyv;
    for (int k = 0; k < KSAMP; ++k) {
      float bv = v; int bi = t;
#pragma unroll
      for (int mm = 32; mm >= 1; mm >>= 1) {
        float ov = __shfl_xor(bv, mm);
        int   oi = __shfl_xor(bi, mm);
        if (ov > bv || (ov == bv && oi < bi)) { bv = ov; bi = oi; }
      }
      if (t == 0) out_action[(size_t)n * KSAMP + k] = (float)bi;
      if (t == bi) v = -3.402823466e+38f;
    }
  }
}

extern "C" void kernel_launch(void* const* d_in, const int* in_sizes, int n_in,
                              void* d_out, int out_size, void* d_ws, size_t ws_size,
                              hipStream_t stream) {
  const float* rootf = (const float*)d_in[0];
  const float* rts   = (const float*)d_in[1];
  const float* nf    = (const float*)d_in[2];
  const float* ef    = (const float*)d_in[3];
  const float* nts   = (const float*)d_in[4];
  const int*   nid   = (const int*)d_in[5];
  const float* Wn    = (const float*)d_in[6];
  const float* bn    = (const float*)d_in[7];
  const float* We    = (const float*)d_in[8];
  const float* be    = (const float*)d_in[9];
  const float* Wl    = (const float*)d_in[10];
  const float* Wr    = (const float*)d_in[11];

  const int n = in_sizes[1];                   // 4096 rows
  float* probs  = (float*)d_out;               // [n,64] f32
  float* action = probs + (size_t)n * B;       // [n,16] written as f32 values

  AdaptSampler_kernel<<<dim3(n), dim3(THREADS), 0, stream>>>(
      rootf, rts, nf, ef, nts, nid, Wn, bn, We, be, Wl, Wr, probs, action);
}

// Round 5
// 963.844 us; speedup vs baseline: 1.4273x; 1.3663x over previous
//
#include <hip/hip_runtime.h>
#include <cstdint>
#include <math.h>

#define B       64
#define DF      172
#define HDIM    256
#define KSAMP   16
#define THREADS 512

typedef const __attribute__((address_space(1))) unsigned int* gp_t;
typedef __attribute__((address_space(3))) unsigned int* lp_t;

// NOTE: parameter names must not collide with float4 member accessors (.x/.y/.z/.w)
#define FMA4(A_, S_, W_) \
  A_.x = fmaf(S_, W_.x, A_.x); A_.y = fmaf(S_, W_.y, A_.y); \
  A_.z = fmaf(S_, W_.z, A_.z); A_.w = fmaf(S_, W_.w, A_.w);

// ---------------- threefry2x32 (bit-exact vs JAX, partitionable scheme) ----------------
__device__ __forceinline__ uint32_t rotl32(uint32_t x, int d) {
  return (x << d) | (x >> (32 - d));
}

__device__ __forceinline__ void threefry2x32(uint32_t k0, uint32_t k1,
                                             uint32_t& x0, uint32_t& x1) {
  const uint32_t ks0 = k0, ks1 = k1, ks2 = k0 ^ k1 ^ 0x1BD11BDAu;
  x0 += ks0; x1 += ks1;
#define TF_R4(ra,rb,rc,rd) \
  x0 += x1; x1 = rotl32(x1, ra); x1 ^= x0; \
  x0 += x1; x1 = rotl32(x1, rb); x1 ^= x0; \
  x0 += x1; x1 = rotl32(x1, rc); x1 ^= x0; \
  x0 += x1; x1 = rotl32(x1, rd); x1 ^= x0;
  TF_R4(13,15,26,6)  x0 += ks1; x1 += ks2 + 1u;
  TF_R4(17,29,16,24) x0 += ks2; x1 += ks0 + 2u;
  TF_R4(13,15,26,6)  x0 += ks0; x1 += ks1 + 3u;
  TF_R4(17,29,16,24) x0 += ks1; x1 += ks2 + 4u;
  TF_R4(13,15,26,6)  x0 += ks2; x1 += ks0 + 5u;
#undef TF_R4
}

// ---------------- async stage 44032 B (2752 float4) global -> LDS ----------------
__device__ __forceinline__ void stage_async(const float* __restrict__ g,
                                            float* l, int t) {
#pragma unroll
  for (int it = 0; it < 5; ++it) {
    const int i  = it * 512 + t;
    const int ib = it * 512 + (t & ~63);   // wave-uniform LDS base
    __builtin_amdgcn_global_load_lds((gp_t)(g + i * 4), (lp_t)(l + ib * 4), 16, 0, 0);
  }
  if (t < 192) {                           // tail: 3 full waves
    const int i  = 2560 + t;
    const int ib = 2560 + (t & ~63);
    __builtin_amdgcn_global_load_lds((gp_t)(g + i * 4), (lp_t)(l + ib * 4), 16, 0, 0);
  }
}

// ---------------- encode GEMM: [64 x 172] @ [172 x 64] + bias, relu ----------------
// thread (b2 = t>>4: rows 2*b2, 2*b2+1; cg = t&15: cols 4cg..4cg+3)
__device__ __forceinline__ void enc_gemm(const float* __restrict__ stage,
                                         const float* __restrict__ W,
                                         const float* __restrict__ bias,
                                         float* __restrict__ out,
                                         int b2, int cg) {
  const float4* W4 = (const float4*)W;                       // [172][16]
  const float4* A0 = (const float4*)(stage + (2 * b2) * DF); // 688B row stride, 16B aligned
  const float4* A1 = (const float4*)(stage + (2 * b2 + 1) * DF);
  float4 acc0 = ((const float4*)bias)[cg];
  float4 acc1 = acc0;
  float4 w0 = W4[0 * 16 + cg], w1 = W4[1 * 16 + cg];
  float4 w2 = W4[2 * 16 + cg], w3 = W4[3 * 16 + cg];
  for (int k = 0; k < DF; k += 4) {
    const float4 wa = w0, wb = w1, wc = w2, wd = w3;
    if (k < DF - 4) {
      w0 = W4[(k + 4) * 16 + cg]; w1 = W4[(k + 5) * 16 + cg];
      w2 = W4[(k + 6) * 16 + cg]; w3 = W4[(k + 7) * 16 + cg];
    }
    const float4 x0 = A0[k >> 2];
    const float4 x1 = A1[k >> 2];
    FMA4(acc0, x0.x, wa) FMA4(acc0, x0.y, wb) FMA4(acc0, x0.z, wc) FMA4(acc0, x0.w, wd)
    FMA4(acc1, x1.x, wa) FMA4(acc1, x1.y, wb) FMA4(acc1, x1.z, wc) FMA4(acc1, x1.w, wd)
  }
  float4 o0 = make_float4(fmaxf(acc0.x, 0.f), fmaxf(acc0.y, 0.f), fmaxf(acc0.z, 0.f), fmaxf(acc0.w, 0.f));
  float4 o1 = make_float4(fmaxf(acc1.x, 0.f), fmaxf(acc1.y, 0.f), fmaxf(acc1.z, 0.f), fmaxf(acc1.w, 0.f));
  ((float4*)out)[(2 * b2) * 16 + cg]     = o0;
  ((float4*)out)[(2 * b2 + 1) * 16 + cg] = o1;
}

// ---------------- h_link piece accumulate: acc[8 rows][4 h] += enc @ Wl[off:off+64, 4c..4c+3]
// Wlp = ((const float4*)Wl) + off*64 + c  (col-group c = t&63: coalesced 1KB/row per wave)
__device__ __forceinline__ void accum_piece(float4 (&acc)[8],
                                            const float* __restrict__ enc, int r8,
                                            const float4* __restrict__ Wlp) {
  float4 w0 = Wlp[0], w1 = Wlp[64], w2 = Wlp[128], w3 = Wlp[192];
  for (int d0 = 0; d0 < 64; d0 += 4) {
    const float4 wa = w0, wb = w1, wc = w2, wd = w3;
    if (d0 < 60) {
      const float4* p = Wlp + (d0 + 4) * 64;
      w0 = p[0]; w1 = p[64]; w2 = p[128]; w3 = p[192];
    }
#pragma unroll
    for (int i = 0; i < 8; ++i) {
      const float4 e = *(const float4*)&enc[(r8 + i) * 64 + d0];  // wave-uniform broadcast
      FMA4(acc[i], e.x, wa) FMA4(acc[i], e.y, wb) FMA4(acc[i], e.z, wc) FMA4(acc[i], e.w, wd)
    }
  }
}

__global__ __launch_bounds__(THREADS, 4)
void AdaptSampler_kernel(const float* __restrict__ rootf,   // [n,172]
                         const float* __restrict__ root_ts, // [n]
                         const float* __restrict__ nf,      // [n,64,172]
                         const float* __restrict__ ef,      // [n,64,172]
                         const float* __restrict__ nts,     // [n,64]
                         const int*   __restrict__ nid,     // [n,64]
                         const float* __restrict__ Wn,      // [172,64]
                         const float* __restrict__ bn,      // [64]
                         const float* __restrict__ We,      // [172,64]
                         const float* __restrict__ be,      // [64]
                         const float* __restrict__ Wl,      // [320,256]
                         const float* __restrict__ Wr,      // [192,256]
                         float* __restrict__ out_probs,     // [n,64]
                         float* __restrict__ out_action)    // [n,16] (as float)
{
  __shared__ float nf_stage[B * DF];    // 44032 B: nf then ef
  __shared__ float encA[B * 64];        // 16384 B: node_enc -> edge_enc -> freq_enc
  __shared__ float encB[B * 64];        // 16384 B: time_enc
  __shared__ float hroot_lds[HDIM];
  __shared__ float rootenc_lds[192];
  __shared__ float w_lds[B];
  __shared__ float ts_lds[B];
  __shared__ __align__(16) int nid_lds[B];
  __shared__ float freq_lds[B];
  __shared__ float sc_lds[B];
  // total 79872 B -> 2 blocks/CU

  const int n = blockIdx.x;
  const int t = threadIdx.x;
  const int c  = t & 63;          // accum col-group (4 h)
  const int r8 = (t >> 6) * 8;    // accum row base (8 rows)
  const int b2 = t >> 4;          // enc row-pair
  const int cg = t & 15;          // enc col-group
  const float4* Wl4 = (const float4*)Wl;  // [320][64]

  // ---------------- P0: stage nf; wave 7: basis/nid/ts + root_feat (serial per col) ----------------
  stage_async(nf + (size_t)n * B * DF, nf_stage, t);
  if (t >= 448) {
    const int j = t - 448;
    double e = 9.0 * (double)j / 63.0;   // np.linspace in f64
    const float wj = (float)(1.0 / pow(10.0, e));
    w_lds[j]   = wj;
    nid_lds[j] = nid[n * B + j];
    ts_lds[j]  = nts[n * B + j];
    float a = bn[j];
    const float* rr = rootf + (size_t)n * DF;
#pragma unroll 4
    for (int d = 0; d < DF; ++d) a = fmaf(rr[d], Wn[d * 64 + j], a);
    rootenc_lds[j]       = fmaxf(a, 0.0f);
    rootenc_lds[64 + j]  = 1.0f;         // cos(0*w)
    rootenc_lds[128 + j] = cosf(wj);     // cos(1*w)
  }
  __syncthreads();

  // ---------------- P1: node_enc -> encA; time_enc -> encB; h_root; freq count ----------------
  enc_gemm(nf_stage, Wn, bn, encA, b2, cg);
  {
    const float rts = root_ts[n];
#pragma unroll
    for (int q = 0; q < 8; ++q) {
      const int idx = q * 512 + t;       // stride-1 across lanes: conflict-free
      const int bb = idx >> 6, dd = idx & 63;
      encB[idx] = cosf((rts - ts_lds[bb]) * w_lds[dd]);
    }
  }
  {
    const int h = t >> 1, hf = t & 1;
    float a = 0.0f;
    for (int d = hf * 96; d < hf * 96 + 96; ++d)
      a = fmaf(rootenc_lds[d], Wr[d * HDIM + h], a);
    a += __shfl_xor(a, 1);
    if (hf == 0) hroot_lds[h] = fmaxf(a, 0.0f);
  }
  if (t >= 448) {
    const int j = t - 448;
    int cnt = 0; const int my = nid_lds[j];
    for (int k = 0; k < B; ++k) cnt += (nid_lds[k] == my) ? 1 : 0;
    freq_lds[j] = (float)cnt * 0.015625f;
  }
  __syncthreads();

  // ---------------- P2: issue ef stage; accum node (d 0..63) ----------------
  stage_async(ef + (size_t)n * B * DF, nf_stage, t);
  float4 acc[8];
#pragma unroll
  for (int i = 0; i < 8; ++i) acc[i] = make_float4(0.f, 0.f, 0.f, 0.f);
  accum_piece(acc, encA, r8, Wl4 + c);
  __syncthreads();

  // ---------------- P3: edge_enc -> encA ----------------
  enc_gemm(nf_stage, We, be, encA, b2, cg);
  __syncthreads();

  // ---------------- P4: accum edge (d 64..127) ----------------
  accum_piece(acc, encA, r8, Wl4 + 64 * 64 + c);
  __syncthreads();

  // ---------------- P5: freq_enc -> encA ----------------
#pragma unroll
  for (int q = 0; q < 8; ++q) {
    const int idx = q * 512 + t;
    const int bb = idx >> 6, dd = idx & 63;
    encA[idx] = cosf(freq_lds[bb] * w_lds[dd]);
  }
  __syncthreads();

  // ---------------- P6: accum time (128..191), freq (192..255), iden (256..319); scores ----------------
  accum_piece(acc, encB, r8, Wl4 + 128 * 64 + c);
  accum_piece(acc, encA, r8, Wl4 + 192 * 64 + c);
  {
    int nr[8];
#pragma unroll
    for (int i = 0; i < 8; ++i) nr[i] = nid_lds[r8 + i];
    const float4* Wlp = Wl4 + 256 * 64 + c;
    float4 w0 = Wlp[0], w1 = Wlp[64], w2 = Wlp[128], w3 = Wlp[192];
    for (int d0 = 0; d0 < 64; d0 += 4) {
      const float4 wa = w0, wb = w1, wc = w2, wd = w3;
      if (d0 < 60) {
        const float4* p = Wlp + (d0 + 4) * 64;
        w0 = p[0]; w1 = p[64]; w2 = p[128]; w3 = p[192];
      }
      const int4 nd = *(const int4*)&nid_lds[d0];
#pragma unroll
      for (int i = 0; i < 8; ++i) {
        const float e0 = (nr[i] == nd.x) ? 1.0f : 0.0f;
        const float e1 = (nr[i] == nd.y) ? 1.0f : 0.0f;
        const float e2 = (nr[i] == nd.z) ? 1.0f : 0.0f;
        const float e3 = (nr[i] == nd.w) ? 1.0f : 0.0f;
        FMA4(acc[i], e0, wa) FMA4(acc[i], e1, wb) FMA4(acc[i], e2, wc) FMA4(acc[i], e3, wd)
      }
    }
  }
  {
    const float4 hr = ((const float4*)hroot_lds)[c];
#pragma unroll
    for (int i = 0; i < 8; ++i) {
      float s;
      s = fmaxf(acc[i].x, 0.f) * hr.x;
      s = fmaf(fmaxf(acc[i].y, 0.f), hr.y, s);
      s = fmaf(fmaxf(acc[i].z, 0.f), hr.z, s);
      s = fmaf(fmaxf(acc[i].w, 0.f), hr.w, s);
#pragma unroll
      for (int m = 32; m >= 1; m >>= 1) s += __shfl_xor(s, m);
      if (c == 0) sc_lds[r8 + i] = s;
    }
  }
  __syncthreads();

  // ---------------- P7: softmax + gumbel + top-16 (wave 0) ----------------
  if (t < B) {
    float s = sc_lds[t] * 0.0625f;   // / sqrt(256)
    float m = s;
#pragma unroll
    for (int mm = 32; mm >= 1; mm >>= 1) m = fmaxf(m, __shfl_xor(m, mm));
    float e = expf(s - m);
    float sum = e;
#pragma unroll
    for (int mm = 32; mm >= 1; mm >>= 1) sum += __shfl_xor(sum, mm);
    float p = e / sum;
    out_probs[(size_t)n * B + t] = p;

    // partitionable threefry: block input (0, i), draw = out0 ^ out1
    uint32_t i = (uint32_t)(n * B + t);
    uint32_t x0 = 0u, x1 = i;
    threefry2x32(0u, 42u, x0, x1);
    uint32_t bits = x0 ^ x1;
    float f = __uint_as_float((bits >> 9) | 0x3f800000u) - 1.0f;
    const float TINY = 1.1754943508222875e-38f;
    float u = fmaxf(f * (1.0f - TINY) + TINY, TINY);
    float g = -logf(-logf(u));
    float keyv = logf(p + 1e-20f) + g;

    float v = keyv;
    for (int k = 0; k < KSAMP; ++k) {
      float bv = v; int bi = t;
#pragma unroll
      for (int mm = 32; mm >= 1; mm >>= 1) {
        float ov = __shfl_xor(bv, mm);
        int   oi = __shfl_xor(bi, mm);
        if (ov > bv || (ov == bv && oi < bi)) { bv = ov; bi = oi; }
      }
      if (t == 0) out_action[(size_t)n * KSAMP + k] = (float)bi;
      if (t == bi) v = -3.402823466e+38f;
    }
  }
}

extern "C" void kernel_launch(void* const* d_in, const int* in_sizes, int n_in,
                              void* d_out, int out_size, void* d_ws, size_t ws_size,
                              hipStream_t stream) {
  const float* rootf = (const float*)d_in[0];
  const float* rts   = (const float*)d_in[1];
  const float* nf    = (const float*)d_in[2];
  const float* ef    = (const float*)d_in[3];
  const float* nts   = (const float*)d_in[4];
  const int*   nid   = (const int*)d_in[5];
  const float* Wn    = (const float*)d_in[6];
  const float* bn    = (const float*)d_in[7];
  const float* We    = (const float*)d_in[8];
  const float* be    = (const float*)d_in[9];
  const float* Wl    = (const float*)d_in[10];
  const float* Wr    = (const float*)d_in[11];

  const int n = in_sizes[1];                   // 4096 rows
  float* probs  = (float*)d_out;               // [n,64] f32
  float* action = probs + (size_t)n * B;       // [n,16] written as f32 values

  AdaptSampler_kernel<<<dim3(n), dim3(THREADS), 0, stream>>>(
      rootf, rts, nf, ef, nts, nid, Wn, bn, We, be, Wl, Wr, probs, action);
}